// Round 5
// baseline (146.508 us; speedup 1.0000x reference)
//
#include <hip/hip_runtime.h>

// N=16384 rows, D=1024 fp32. loss = mean_r(1 - cos(pc[r], aug[r]))
// R1-R4: ~42-46us @ 3.2 TB/s effective read, invariant to occupancy,
// rows/wave, structure, and HBM-vs-L3 residence. Compiler pins VGPR at
// 24-40 -> never more than ~4 loads in flight. R5: global_load_lds async
// DMA staging (no VGPR destinations, deep vmcnt queue), wave-private LDS
// double buffer, manual vmcnt waits, reductions deferred past the stream.

#define N_ROWS 16384
#define TPB 256
#define WPB 4                       // waves per block
#define RPW 8                       // rows per wave
#define BLOCKS (N_ROWS / (WPB * RPW))   // 512 blocks -> 2 blocks/CU resident

typedef const __attribute__((address_space(1))) unsigned int* gas_u32;
typedef __attribute__((address_space(3))) unsigned int* las_u32;

template<int N> __device__ __forceinline__ void wait_vmcnt() {
    asm volatile("s_waitcnt vmcnt(%0)" :: "n"(N) : "memory");
}

// Stage one row of A (4KB) + one row of B (4KB) into ldsbuf[0..2047] floats.
// 8 x global_load_lds dwordx4: each moves 64 lanes x 16B = 1KB, gptr is a
// perfect contiguous 1KB segment, lds dest = uniform base + lane*16.
__device__ __forceinline__ void stage_row(const float* gA, const float* gB,
                                          float* ldsbuf, int lane) {
    #pragma unroll
    for (int j = 0; j < 4; ++j)
        __builtin_amdgcn_global_load_lds((gas_u32)(gA + j * 256 + lane * 4),
                                         (las_u32)(ldsbuf + j * 256), 16, 0, 0);
    #pragma unroll
    for (int j = 0; j < 4; ++j)
        __builtin_amdgcn_global_load_lds((gas_u32)(gB + j * 256 + lane * 4),
                                         (las_u32)(ldsbuf + 1024 + j * 256), 16, 0, 0);
}

// Consume 2 staged rows: lane k reads float4s at consecutive 16B -> ds_read_b128
// conflict-free. 48 FMAs into the 3 partials.
__device__ __forceinline__ void consume_row(const float* ldsbuf, int lane,
                                            float& ab, float& aa, float& bb) {
    const float4* A = (const float4*)ldsbuf;
    const float4* B = (const float4*)(ldsbuf + 1024);
    float4 x[4], y[4];
    #pragma unroll
    for (int k = 0; k < 4; ++k) { x[k] = A[lane + 64 * k]; y[k] = B[lane + 64 * k]; }
    float tab = 0, taa = 0, tbb = 0;
    #pragma unroll
    for (int k = 0; k < 4; ++k) {
        tab += x[k].x * y[k].x + x[k].y * y[k].y + x[k].z * y[k].z + x[k].w * y[k].w;
        taa += x[k].x * x[k].x + x[k].y * x[k].y + x[k].z * x[k].z + x[k].w * x[k].w;
        tbb += y[k].x * y[k].x + y[k].y * y[k].y + y[k].z * y[k].z + y[k].w * y[k].w;
    }
    ab = tab; aa = taa; bb = tbb;
}

__global__ __launch_bounds__(TPB) void cos_rows_kernel(
    const float* __restrict__ a, const float* __restrict__ b,
    float* __restrict__ partial)
{
    __shared__ float lds[WPB][2][2048];   // 64 KB: per-wave private dbuf
    __shared__ float s[WPB];
    const int wave = threadIdx.x >> 6;
    const int lane = threadIdx.x & 63;
    const int r0 = (blockIdx.x * WPB + wave) * RPW;

    const float* ga = a + (size_t)r0 * 1024;
    const float* gb = b + (size_t)r0 * 1024;

    float ab[RPW], aa[RPW], bb[RPW];

    stage_row(ga, gb, lds[wave][0], lane);
    #pragma unroll
    for (int i = 0; i < RPW; ++i) {
        if (i < RPW - 1) {
            stage_row(ga + (size_t)(i + 1) * 1024, gb + (size_t)(i + 1) * 1024,
                      lds[wave][(i + 1) & 1], lane);
            wait_vmcnt<8>();     // batch i landed; batch i+1 still in flight
        } else {
            wait_vmcnt<0>();
        }
        consume_row(lds[wave][i & 1], lane, ab[i], aa[i], bb[i]);
    }

    // Deferred reductions (off the load stream).
    #pragma unroll
    for (int i = 0; i < RPW; ++i) {
        #pragma unroll
        for (int off = 32; off > 0; off >>= 1) {
            ab[i] += __shfl_down(ab[i], off);
            aa[i] += __shfl_down(aa[i], off);
            bb[i] += __shfl_down(bb[i], off);
        }
    }
    if (lane == 0) {
        float t = 0.0f;
        #pragma unroll
        for (int i = 0; i < RPW; ++i) {
            float na = fmaxf(sqrtf(aa[i]), 1e-12f);
            float nb = fmaxf(sqrtf(bb[i]), 1e-12f);
            t += ab[i] / (na * nb);
        }
        s[wave] = t;
    }
    __syncthreads();
    if (threadIdx.x == 0) {
        float t = 0.0f;
        #pragma unroll
        for (int i = 0; i < WPB; ++i) t += s[i];
        partial[blockIdx.x] = t;
    }
}

__global__ __launch_bounds__(512) void finalize_kernel(
    const float* __restrict__ partial, float* __restrict__ out)
{
    const int wave = threadIdx.x >> 6;
    const int lane = threadIdx.x & 63;
    float t = partial[threadIdx.x];   // BLOCKS == 512 == blockDim
    #pragma unroll
    for (int off = 32; off > 0; off >>= 1) t += __shfl_down(t, off);
    __shared__ float s[512 / 64];
    if (lane == 0) s[wave] = t;
    __syncthreads();
    if (threadIdx.x == 0) {
        float tot = 0.0f;
        #pragma unroll
        for (int i = 0; i < 512 / 64; ++i) tot += s[i];
        out[0] = 1.0f - tot / (float)N_ROWS;
    }
}

extern "C" void kernel_launch(void* const* d_in, const int* in_sizes, int n_in,
                              void* d_out, int out_size, void* d_ws, size_t ws_size,
                              hipStream_t stream) {
    const float* pc  = (const float*)d_in[0];
    const float* aug = (const float*)d_in[1];
    float* partial = (float*)d_ws;       // BLOCKS floats = 2 KiB scratch
    float* out = (float*)d_out;

    cos_rows_kernel<<<BLOCKS, TPB, 0, stream>>>(pc, aug, partial);
    finalize_kernel<<<1, 512, 0, stream>>>(partial, out);
}